// Round 2
// 697.804 us; speedup vs baseline: 1.2011x; 1.2011x over previous
//
#include <hip/hip_runtime.h>
#include <hip/hip_bf16.h>

#define N_USER 100000
#define N_PHOTO 200000
#define NEDGE 1000000
#define INF 256
#define OUTF 64

typedef unsigned short u16;
typedef __attribute__((ext_vector_type(8))) short short8;
typedef __attribute__((ext_vector_type(4))) float f32x4;

#define LDSPAD 264       // 256 + 8 pad: keeps 16B alignment, breaks pow2 bank stride
#define SCAN_CHUNK 2048  // ints per chunk in the hierarchical scan
#define NBP 98           // ceil(N_PHOTO / SCAN_CHUNK)
#define NBU 49           // ceil(N_USER  / SCAN_CHUNK)

// f32 -> bf16 bits, round-to-nearest-even
__device__ inline u16 f2b(float f) {
    union { float f; unsigned u; } v; v.f = f;
    unsigned r = v.u + 0x7FFF + ((v.u >> 16) & 1);
    return (u16)(r >> 16);
}
__device__ inline float b2f(u16 h) {
    union { unsigned u; float f; } v; v.u = ((unsigned)h) << 16; return v.f;
}

// ---- dispatch 1: transpose both W -> bf16 Wt; zero deg arrays (1.2MB, int4) ----
// deg_photo and deg_user are contiguous in ws: zero as one 300000-int region.
__global__ __launch_bounds__(256) void prep0(const float* __restrict__ W_likes,
                                             const float* __restrict__ W_likedby,
                                             u16* __restrict__ Wt_likes,
                                             u16* __restrict__ Wt_likedby,
                                             int* __restrict__ deg_base) {
    int i = blockIdx.x * 256 + threadIdx.x;    // 75008 threads
    if (i < 75000) {
        int4 z = {0, 0, 0, 0};
        ((int4*)deg_base)[i] = z;
    }
    if (i < INF * OUTF) {
        int n = i & (OUTF - 1), k = i >> 6;
        Wt_likes[n * INF + k]   = f2b(W_likes[i]);
        Wt_likedby[n * INF + k] = f2b(W_likedby[i]);
    }
}

// ---- dispatch 2: Wh = feats @ W + b for BOTH etypes; bf16 MFMA ----
__global__ __launch_bounds__(256) void proj_both(
    const float* __restrict__ user_feats, const float* __restrict__ photo_feats,
    const u16* __restrict__ Wt_likes, const u16* __restrict__ Wt_likedby,
    const float* __restrict__ b_likes, const float* __restrict__ b_likedby,
    u16* __restrict__ Wh_likes, u16* __restrict__ Wh_likedby)
{
    __shared__ u16 lds_wt[OUTF * LDSPAD];   // 33792 B -> 4 blocks/CU
    const int NB_USER_PROJ = (N_USER + 63) / 64;   // 1563
    int bb = blockIdx.x;
    const float* feats; const u16* Wt; const float* bias; u16* Wh; int nrows; int blk;
    if (bb < NB_USER_PROJ) { feats = user_feats;  Wt = Wt_likes;   bias = b_likes;   Wh = Wh_likes;   nrows = N_USER;  blk = bb; }
    else                   { feats = photo_feats; Wt = Wt_likedby; bias = b_likedby; Wh = Wh_likedby; nrows = N_PHOTO; blk = bb - NB_USER_PROJ; }

    int tid = threadIdx.x;
    for (int c = tid; c < (INF * OUTF) / 8; c += 256) {
        int n = c >> 5;
        int ko = (c & 31) * 8;
        *(short8*)&lds_wt[n * LDSPAD + ko] = *(const short8*)&Wt[n * INF + ko];
    }
    __syncthreads();

    int wave = tid >> 6, lane = tid & 63;
    int l15 = lane & 15, quad = lane >> 4;
    int r0 = blk * 64 + wave * 16;
    int arow = r0 + l15;
    bool arow_ok = arow < nrows;

    f32x4 acc[4] = {{0,0,0,0},{0,0,0,0},{0,0,0,0},{0,0,0,0}};
    const float4* ap = (const float4*)(feats + (size_t)(arow_ok ? arow : 0) * INF);

    #pragma unroll
    for (int ks = 0; ks < 8; ++ks) {
        float4 x = ap[ks * 8 + quad * 2 + 0];   // A[m=arow][k=ks*32+quad*8+j]
        float4 y = ap[ks * 8 + quad * 2 + 1];
        short8 a = { (short)f2b(x.x), (short)f2b(x.y), (short)f2b(x.z), (short)f2b(x.w),
                     (short)f2b(y.x), (short)f2b(y.y), (short)f2b(y.z), (short)f2b(y.w) };
        #pragma unroll
        for (int nt2 = 0; nt2 < 4; ++nt2) {
            short8 b = *(const short8*)&lds_wt[(nt2 * 16 + l15) * LDSPAD + ks * 32 + quad * 8];
            acc[nt2] = __builtin_amdgcn_mfma_f32_16x16x32_bf16(a, b, acc[nt2], 0, 0, 0);
        }
    }

    #pragma unroll
    for (int nt2 = 0; nt2 < 4; ++nt2) {
        int col = nt2 * 16 + l15;
        float bv = bias[col];
        #pragma unroll
        for (int r = 0; r < 4; ++r) {
            int row = r0 + quad * 4 + r;    // D: row=quad*4+reg, col=lane&15 (+16*nt)
            if (row < nrows) {
                Wh[(size_t)row * OUTF + col] = f2b(acc[nt2][r] + bv);
            }
        }
    }
}

// ---- dispatch 3: degree count, both etypes, int4 edge reads (4 edges/thread) ----
__global__ __launch_bounds__(256) void count_both(const int* __restrict__ likes_dst,
                                                  const int* __restrict__ likedby_dst,
                                                  int* __restrict__ deg_photo,
                                                  int* __restrict__ deg_user) {
    int i = blockIdx.x * 256 + threadIdx.x;   // 250112 threads for 250000 int4s
    if (i < NEDGE / 4) {
        int4 a = ((const int4*)likes_dst)[i];
        atomicAdd(&deg_photo[a.x], 1); atomicAdd(&deg_photo[a.y], 1);
        atomicAdd(&deg_photo[a.z], 1); atomicAdd(&deg_photo[a.w], 1);
        int4 b = ((const int4*)likedby_dst)[i];
        atomicAdd(&deg_user[b.x], 1); atomicAdd(&deg_user[b.y], 1);
        atomicAdd(&deg_user[b.z], 1); atomicAdd(&deg_user[b.w], 1);
    }
}

// ---- dispatch 4: per-2048-chunk sums, both etypes (blocks 0..NBP-1 photo, rest user) ----
__global__ __launch_bounds__(256) void sums_both(const int* __restrict__ deg_photo,
                                                 const int* __restrict__ deg_user,
                                                 int* __restrict__ bsums_photo,
                                                 int* __restrict__ bsums_user) {
    __shared__ int lds[256];
    int c = blockIdx.x, t = threadIdx.x;
    const int* deg; int* bs; int n; int cc;
    if (c < NBP) { deg = deg_photo; bs = bsums_photo; n = N_PHOTO; cc = c; }
    else         { deg = deg_user;  bs = bsums_user;  n = N_USER;  cc = c - NBP; }
    int s = 0;
    #pragma unroll
    for (int t2 = 0; t2 < 2; ++t2) {
        int i4 = cc * 512 + t2 * 256 + t;
        if (i4 * 4 < n) { int4 v = ((const int4*)deg)[i4]; s += v.x + v.y + v.z + v.w; }
    }
    lds[t] = s;
    __syncthreads();
    for (int ofs = 128; ofs > 0; ofs >>= 1) {
        if (t < ofs) lds[t] += lds[t + ofs];
        __syncthreads();
    }
    if (t == 0) bs[cc] = lds[0];
}

// ---- dispatch 5: exclusive scan of chunk sums (block 0 photo, block 1 user) ----
__global__ __launch_bounds__(256) void scanb_both(int* __restrict__ bsums_photo,
                                                  int* __restrict__ bsums_user,
                                                  int* __restrict__ off_photo,
                                                  int* __restrict__ off_user) {
    __shared__ int lds[256];
    int t = threadIdx.x;
    int* bs; int nb2; int* offend;
    if (blockIdx.x == 0) { bs = bsums_photo; nb2 = NBP; offend = off_photo + N_PHOTO; }
    else                 { bs = bsums_user;  nb2 = NBU; offend = off_user  + N_USER; }
    int v = (t < nb2) ? bs[t] : 0;
    lds[t] = v;
    __syncthreads();
    for (int ofs = 1; ofs < 256; ofs <<= 1) {
        int add = (t >= ofs) ? lds[t - ofs] : 0;
        __syncthreads();
        lds[t] += add;
        __syncthreads();
    }
    if (t < nb2) bs[t] = lds[t] - v;   // exclusive chunk base
    if (t == 0) *offend = lds[255];    // grand total
}

// ---- dispatch 6: per-chunk local scan + base -> off, cursor; both etypes ----
__global__ __launch_bounds__(256) void apply_both(
    const int* __restrict__ deg_photo, const int* __restrict__ deg_user,
    const int* __restrict__ bsums_photo, const int* __restrict__ bsums_user,
    int* __restrict__ off_photo, int* __restrict__ off_user,
    int* __restrict__ cursor_photo, int* __restrict__ cursor_user) {
    __shared__ int lds[256];
    int c = blockIdx.x, t = threadIdx.x;
    const int* deg; const int* bs; int* off; int* cur; int n; int cc;
    if (c < NBP) { deg = deg_photo; bs = bsums_photo; off = off_photo; cur = cursor_photo; n = N_PHOTO; cc = c; }
    else         { deg = deg_user;  bs = bsums_user;  off = off_user;  cur = cursor_user;  n = N_USER;  cc = c - NBP; }
    int base = bs[cc];
    #pragma unroll
    for (int t2 = 0; t2 < 2; ++t2) {
        int i4 = cc * 512 + t2 * 256 + t;
        int4 v = {0, 0, 0, 0};
        bool ok = i4 * 4 < n;
        if (ok) v = ((const int4*)deg)[i4];
        int s4 = v.x + v.y + v.z + v.w;
        lds[t] = s4;
        __syncthreads();
        for (int ofs = 1; ofs < 256; ofs <<= 1) {
            int vv = (t >= ofs) ? lds[t - ofs] : 0;
            __syncthreads();
            lds[t] += vv;
            __syncthreads();
        }
        int excl = base + lds[t] - s4;
        if (ok) {
            int4 o;
            o.x = excl; o.y = o.x + v.x; o.z = o.y + v.y; o.w = o.z + v.z;
            ((int4*)off)[i4] = o;
            ((int4*)cur)[i4] = o;
        }
        base += lds[255];
        __syncthreads();
    }
}

// ---- dispatch 7: scatter edge src ids grouped by dst, both etypes, int4 reads ----
__global__ __launch_bounds__(256) void scatter_both(
    const int* __restrict__ likes_src, const int* __restrict__ likes_dst,
    const int* __restrict__ likedby_src, const int* __restrict__ likedby_dst,
    int* __restrict__ cursor_photo, int* __restrict__ cursor_user,
    int* __restrict__ perm_likes, int* __restrict__ perm_likedby) {
    int i = blockIdx.x * 256 + threadIdx.x;
    if (i < NEDGE / 4) {
        int4 s = ((const int4*)likes_src)[i];
        int4 d = ((const int4*)likes_dst)[i];
        perm_likes[atomicAdd(&cursor_photo[d.x], 1)] = s.x;
        perm_likes[atomicAdd(&cursor_photo[d.y], 1)] = s.y;
        perm_likes[atomicAdd(&cursor_photo[d.z], 1)] = s.z;
        perm_likes[atomicAdd(&cursor_photo[d.w], 1)] = s.w;
        int4 s2 = ((const int4*)likedby_src)[i];
        int4 d2 = ((const int4*)likedby_dst)[i];
        perm_likedby[atomicAdd(&cursor_user[d2.x], 1)] = s2.x;
        perm_likedby[atomicAdd(&cursor_user[d2.y], 1)] = s2.y;
        perm_likedby[atomicAdd(&cursor_user[d2.z], 1)] = s2.z;
        perm_likedby[atomicAdd(&cursor_user[d2.w], 1)] = s2.w;
    }
}

// ---- dispatch 8: gather-mean, both etypes. One wave per dst node.
// 8 lane-groups of 8 lanes each process 8 edges concurrently (8 outstanding
// row loads/wave vs 1 serial); each lane loads 16B (short8).
// Cross-group reduce via 3 shfl_xor; group 0 writes 32B contiguous f32.
__global__ __launch_bounds__(256) void gather_both(
    const u16* __restrict__ Wh_likes, const int* __restrict__ off_photo,
    const int* __restrict__ perm_likes,
    const u16* __restrict__ Wh_likedby, const int* __restrict__ off_user,
    const int* __restrict__ perm_likedby,
    float* __restrict__ out)
{
    int w = blockIdx.x * 4 + (threadIdx.x >> 6);   // N_PHOTO % 4 == 0: no intra-block split
    int lane = threadIdx.x & 63;
    const u16* Wh; const int* off; const int* perm; float* o; int d;
    if (w < N_PHOTO) {
        d = w; Wh = Wh_likes; off = off_photo; perm = perm_likes;
        o = out + (size_t)N_USER * OUTF;
    } else {
        d = w - N_PHOTO;
        if (d >= N_USER) return;
        Wh = Wh_likedby; off = off_user; perm = perm_likedby;
        o = out;
    }
    int g = lane >> 3, sub = lane & 7;
    int e0 = off[d], e1 = off[d + 1];
    float acc[8] = {0.f,0.f,0.f,0.f,0.f,0.f,0.f,0.f};
    for (int j = e0 + g; j < e1; j += 8) {
        int s = perm[j];
        short8 v = *(const short8*)&Wh[(size_t)s * OUTF + sub * 8];
        #pragma unroll
        for (int k = 0; k < 8; ++k) acc[k] += b2f((u16)v[k]);
    }
    float deg = (float)(e1 - e0);
    float inv = 1.0f / (deg > 1.0f ? deg : 1.0f);
    #pragma unroll
    for (int k = 0; k < 8; ++k) {
        float a = acc[k];
        a += __shfl_xor(a, 8, 64);
        a += __shfl_xor(a, 16, 64);
        a += __shfl_xor(a, 32, 64);
        acc[k] = a * inv;
    }
    if (g == 0) {
        float4 o0 = { acc[0], acc[1], acc[2], acc[3] };
        float4 o1 = { acc[4], acc[5], acc[6], acc[7] };
        float* dst = o + (size_t)d * OUTF + sub * 8;
        *(float4*)dst = o0;
        *(float4*)(dst + 4) = o1;
    }
}

extern "C" void kernel_launch(void* const* d_in, const int* in_sizes, int n_in,
                              void* d_out, int out_size, void* d_ws, size_t ws_size,
                              hipStream_t stream) {
    const float* user_feats  = (const float*)d_in[0];
    const float* photo_feats = (const float*)d_in[1];
    const float* W_likes     = (const float*)d_in[2];
    const float* b_likes     = (const float*)d_in[3];
    const float* W_likedby   = (const float*)d_in[4];
    const float* b_likedby   = (const float*)d_in[5];
    const int* likes_src     = (const int*)d_in[6];
    const int* likes_dst     = (const int*)d_in[7];
    const int* likedby_src   = (const int*)d_in[8];
    const int* likedby_dst   = (const int*)d_in[9];

    char* ws = (char*)d_ws;
    // all offsets 16B-aligned; total ~50.1 MB
    u16* Wh_likes     = (u16*)(ws + 0);          // 12,800,000
    u16* Wh_likedby   = (u16*)(ws + 12800000);   // 25,600,000
    u16* Wt_likes     = (u16*)(ws + 38400000);   // 32,768
    u16* Wt_likedby   = (u16*)(ws + 38432768);   // 32,768
    int* deg_photo    = (int*)(ws + 38465536);   // 800,000 } contiguous: zeroed as one
    int* deg_user     = (int*)(ws + 39265536);   // 400,000 } 1.2MB int4 region in prep0
    int* off_photo    = (int*)(ws + 39665536);   // 800,016
    int* off_user     = (int*)(ws + 40465552);   // 400,016
    int* cursor_photo = (int*)(ws + 40865568);   // 800,000
    int* cursor_user  = (int*)(ws + 41665568);   // 400,000
    int* perm_likes   = (int*)(ws + 42065568);   // 4,000,000
    int* perm_likedby = (int*)(ws + 46065568);   // 4,000,000
    int* bsums_photo  = (int*)(ws + 50065568);   // 512
    int* bsums_user   = (int*)(ws + 50066080);   // 512 -> end 50,066,592

    prep0<<<294, 256, 0, stream>>>(W_likes, W_likedby, Wt_likes, Wt_likedby, deg_photo);

    proj_both<<<(N_USER + 63) / 64 + (N_PHOTO + 63) / 64, 256, 0, stream>>>(
        user_feats, photo_feats, Wt_likes, Wt_likedby, b_likes, b_likedby,
        Wh_likes, Wh_likedby);

    count_both<<<(NEDGE / 4 + 255) / 256, 256, 0, stream>>>(
        likes_dst, likedby_dst, deg_photo, deg_user);

    sums_both<<<NBP + NBU, 256, 0, stream>>>(deg_photo, deg_user, bsums_photo, bsums_user);
    scanb_both<<<2, 256, 0, stream>>>(bsums_photo, bsums_user, off_photo, off_user);
    apply_both<<<NBP + NBU, 256, 0, stream>>>(deg_photo, deg_user, bsums_photo, bsums_user,
                                              off_photo, off_user, cursor_photo, cursor_user);

    scatter_both<<<(NEDGE / 4 + 255) / 256, 256, 0, stream>>>(
        likes_src, likes_dst, likedby_src, likedby_dst,
        cursor_photo, cursor_user, perm_likes, perm_likedby);

    gather_both<<<(N_PHOTO + N_USER) / 4, 256, 0, stream>>>(
        Wh_likes, off_photo, perm_likes, Wh_likedby, off_user, perm_likedby,
        (float*)d_out);
}